// Round 3
// baseline (17.870 us; speedup 1.0000x reference)
//
#include <hip/hip_runtime.h>
#include <hip/hip_bf16.h>

// Gather: out[b, s, :] = hidden_states[b, pos[b, s], :]
// B=32, SEQ=4096, SENT=128, DIM=512, fp32.
//
// One wave (64 lanes) per output row:
//   - row index is wave-uniform -> pos fetch becomes one scalar s_load/wave
//   - each lane loads 2 independent float4 (lane, lane+64) from the gathered
//     row (row = 128 float4 = 2 KB, fully coalesced)
//   - nontemporal stores: output is write-once, skip L2 write-allocate
// 4096 rows total -> 4096 waves -> 1024 blocks x 256 threads (4 rows/block).

#define BATCH 32
#define SEQ   4096
#define SENT  128
#define DIM   512
#define DIM4  (DIM / 4)   // 128 float4 per row

// Native clang vector type: required by __builtin_nontemporal_store
// (HIP's float4 is a class and is rejected).
typedef __attribute__((ext_vector_type(4))) float f32x4;

__global__ __launch_bounds__(256) void gather_rows_kernel(
    const f32x4* __restrict__ hs,    // (B, SEQ, DIM/4)
    const int*   __restrict__ pos,   // (B, SENT)
    f32x4*       __restrict__ out)   // (B, SENT, DIM/4)
{
    // Wave-uniform row id in [0, BATCH*SENT). blockDim = 256 = 4 waves.
    const int row = __builtin_amdgcn_readfirstlane(
        (blockIdx.x << 2) | (threadIdx.x >> 6));
    const int lane = threadIdx.x & 63;

    const int b = row >> 7;                 // SENT = 128 = 2^7
    const int p = pos[row];                 // scalar (row uniform) -> s_load

    const f32x4* __restrict__ src = hs + ((size_t)b * SEQ + p) * DIM4;
    f32x4* __restrict__ dst = out + (size_t)row * DIM4;

    // Two independent 16B loads in flight per lane (MLP=2), then stream out.
    f32x4 v0 = src[lane];
    f32x4 v1 = src[lane + 64];
    __builtin_nontemporal_store(v0, dst + lane);
    __builtin_nontemporal_store(v1, dst + lane + 64);
}

extern "C" void kernel_launch(void* const* d_in, const int* in_sizes, int n_in,
                              void* d_out, int out_size, void* d_ws, size_t ws_size,
                              hipStream_t stream) {
    const f32x4* hs  = (const f32x4*)d_in[0];
    const int*   pos = (const int*)d_in[1];
    f32x4*       out = (f32x4*)d_out;

    const int rows = BATCH * SENT;                       // 4096 waves
    gather_rows_kernel<<<rows / 4, 256, 0, stream>>>(hs, pos, out);
}

// Round 4
// 10.402 us; speedup vs baseline: 1.7180x; 1.7180x over previous
//
#include <hip/hip_runtime.h>
#include <hip/hip_bf16.h>

// Gather: out[b, s, :] = hidden_states[b, pos[b, s], :]
// B=32, SEQ=4096, SENT=128, DIM=512, fp32.
//
// R1 structure (best so far, 11.94 us): one thread per float4 of output,
// fully coalesced loads+stores, plain (cached) stores so L2 absorbs the
// 8.4 MB write burst.
// R4 A/B: ONLY change = block geometry 2048x256 -> 512x1024 to cut the
// workgroup dispatch count 4x. Same global thread mapping, same work.

#define BATCH 32
#define SEQ   4096
#define SENT  128
#define DIM   512
#define DIM4  (DIM / 4)   // 128 float4 per row

__global__ __launch_bounds__(1024) void gather_rows_kernel(
    const float4* __restrict__ hs,   // (B, SEQ, DIM/4)
    const int*    __restrict__ pos,  // (B, SENT)
    float4*       __restrict__ out)  // (B, SENT, DIM/4)
{
    const int tid = blockIdx.x * blockDim.x + threadIdx.x;  // [0, 524288)
    const int d   = tid & (DIM4 - 1);       // float4 lane within row
    const int row = tid >> 7;               // (b * SENT + s), DIM4 = 128 = 2^7
    const int b   = row >> 7;               // SENT = 128 = 2^7
    const int p   = pos[row];               // gathered sequence index

    out[tid] = hs[((size_t)b * SEQ + p) * DIM4 + d];
}

extern "C" void kernel_launch(void* const* d_in, const int* in_sizes, int n_in,
                              void* d_out, int out_size, void* d_ws, size_t ws_size,
                              hipStream_t stream) {
    const float4* hs  = (const float4*)d_in[0];
    const int*    pos = (const int*)d_in[1];
    float4*       out = (float4*)d_out;

    const int total4 = BATCH * SENT * DIM4;     // 524288
    gather_rows_kernel<<<total4 / 1024, 1024, 0, stream>>>(hs, pos, out);
}